// Round 12
// baseline (6606.731 us; speedup 1.0000x reference)
//
#include <hip/hip_runtime.h>

// GRU L=512, N=64, H=512, E=256, K=H+E=768.
// Round 12 = round 10 (PASSED: dual-path same-XCD L2 exchange + MALL
// fallback, FETCH proved fast path engages) with the MALL insurance moved
// OFF the critical drains:
//  - publish: plain stores -> vmcnt(0) [L2 ack only] -> plain flag -> MALL
//    data mirror fired with NO wait (drained later, overlapped).
//  - MALL flags: published at the PRE-WAIT point after a vmcnt(0) that the
//    poll's first iteration would pay anyway (in-order vmem retirement =>
//    the previous phase's MALL mirror data is at the coherence point).
//    Own-flag-before-own-poll => no self-deadlock; every block publishes
//    fast flags promptly even when consuming via fallback => producers
//    always pass fast waits and publish deferred MALL flags => no
//    cross-block deadlock.
//  - e-prefetch double-buffered (aeA/aeB), issued at phase-1 end.
//  - FASTBUDGET 300->2000 (startup skew must not latch the slow path).
// r11 lesson: pure-L2 (no fallback) hung twice (r7, r11) despite r10's
// fast path provably engaging -- the fallback is structural, not optional.
// Numerics: fp16 operands, f32 MFMA accum, f32 state (absmax 3.9e-3 r1-r10).

#define LSTEPS 512
#define NBATCH 64
#define HDIM   512
#define EDIM   256
#define KDIM   768
#define NWORK  16
#define COLS   32
#define TPB    256
#define NLAUNCH 128
#define FASTBUDGET 2000

typedef _Float16 f16x8 __attribute__((ext_vector_type(8)));
typedef float    f32x4 __attribute__((ext_vector_type(4)));
typedef unsigned long long u64;

#define MFMA __builtin_amdgcn_mfma_f32_16x16x32_f16
#define VMDRAIN() do { asm volatile("s_waitcnt vmcnt(0)" ::: "memory"); \
                       __builtin_amdgcn_sched_barrier(0); } while (0)

__device__ __forceinline__ float sigm(float x){ return 1.0f/(1.0f+__expf(-x)); }
__device__ __forceinline__ float tanh_fast(float x){
  float e = __expf(2.0f*x);
  return 1.0f - 2.0f/(e + 1.0f);
}
__device__ __forceinline__ unsigned f16b(float x){
  union { _Float16 h; unsigned short u; } c; c.h = (_Float16)x; return (unsigned)c.u;
}
__device__ __forceinline__ f16x8 AFU(u64 a, u64 b){
  union { u64 d[2]; f16x8 v; } c; c.d[0] = a; c.d[1] = b; return c.v;
}

// sc0 load = bypass own L1, read shared L2. Self-contained wait.
__device__ __forceinline__ unsigned ld_sc0_u32(const unsigned* a){
  unsigned r;
  asm volatile("global_load_dword %0, %1, off sc0\n\ts_waitcnt vmcnt(0)"
               : "=v"(r) : "v"(a) : "memory");
  return r;
}

__global__ void prep_w(const float* __restrict__ Wz, const float* __restrict__ Wr,
                       const float* __restrict__ Wh, _Float16* __restrict__ wbuf){
  int tid = blockIdx.x*256 + threadIdx.x;
  int g   = tid / (HDIM*KDIM);
  int rem = tid - g*(HDIM*KDIM);
  int j   = rem / KDIM;
  int k   = rem - j*KDIM;
  const float* W = (g==0) ? Wz : ((g==1) ? Wr : Wh);
  wbuf[tid] = (_Float16)W[(size_t)k*HDIM + j];
}

__global__ void prep_emb(const int* __restrict__ x, const float* __restrict__ emb,
                         _Float16* __restrict__ ebuf){
  int tid = blockIdx.x*256 + threadIdx.x;
  int k4  = tid & 63;
  int tn  = tid >> 6;
  int row = x[tn];
  const float4 v = *(const float4*)(emb + (size_t)row*EDIM + (k4<<2));
  union { _Float16 h[4]; uint2 u; } p;
  p.h[0] = (_Float16)v.x; p.h[1] = (_Float16)v.y;
  p.h[2] = (_Float16)v.z; p.h[3] = (_Float16)v.w;
  *(uint2*)(ebuf + (size_t)tn*EDIM + (k4<<2)) = p.u;
}

// Lane-pair repack of (rows n0..n0+3, col pair) -> two aligned dwords.
__device__ __forceinline__ void pack2(int lane, float v0, float v1, float v2,
                                      float v3, unsigned* w0, unsigned* w1, int* rr){
  unsigned p01 = f16b(v0) | (f16b(v1) << 16);
  unsigned p23 = f16b(v2) | (f16b(v3) << 16);
  unsigned q01 = __shfl_xor(p01, 1, 64);
  unsigned q23 = __shfl_xor(p23, 1, 64);
  if (lane & 1){
    *w0 = (q23 & 0xffffu) | (p23 << 16);
    *w1 = (q23 >> 16)     | (p23 & 0xffff0000u);
    *rr = 2;
  } else {
    *w0 = (p01 & 0xffffu) | (q01 << 16);
    *w1 = (p01 >> 16)     | (q01 & 0xffff0000u);
    *rr = 0;
  }
}

// Wait for all 16 producer flags >= target. Returns 1 if fallback used.
__device__ __forceinline__ int waitx(const unsigned* flL2, const unsigned* flM,
                                     unsigned target, int fpd){
  const int l15 = threadIdx.x & 15;
  if (!fpd){
    for (int i = 0; i < FASTBUDGET; ++i){
      unsigned v = ld_sc0_u32(flL2 + l15);
      if (__all((int)(v >= target))) return 0;
    }
  }
  for (;;){
    unsigned v = __hip_atomic_load(flM + l15, __ATOMIC_RELAXED,
                                   __HIP_MEMORY_SCOPE_AGENT);
    if (__all((int)(v >= target))) break;
  }
  return 1;
}

__global__ __launch_bounds__(TPB, 1) void gru_persist(
    const _Float16* __restrict__ wbuf,   // [3][512][768]
    const _Float16* __restrict__ ebuf,   // [L][64][256]
    const float* __restrict__ bz, const float* __restrict__ br, const float* __restrict__ bh,
    _Float16* __restrict__ hxL, _Float16* __restrict__ hxM,    // [64][512] h
    _Float16* __restrict__ rhL, _Float16* __restrict__ rhM,    // [64][512] r*h
    unsigned* __restrict__ hflL, unsigned* __restrict__ hflM,  // [4][16]
    unsigned* __restrict__ rflL, unsigned* __restrict__ rflM,  // [4][16]
    unsigned* __restrict__ xcnt, unsigned* __restrict__ winner,
    float* __restrict__ out)             // [L][64][512]
{
  __shared__ char wlds[3*COLS*1536];     // 147456 B
  __shared__ int s_slot;

  // ---- XCD claim (r10-proven).
  if (threadIdx.x == 0){
    unsigned xcd;
    asm volatile("s_getreg_b32 %0, hwreg(HW_REG_XCC_ID)" : "=s"(xcd));
    xcd &= 7;
    unsigned rank = __hip_atomic_fetch_add(&xcnt[xcd], 1u,
                        __ATOMIC_RELAXED, __HIP_MEMORY_SCOPE_AGENT);
    int slot = -1;
    if (rank < NWORK){
      if (rank == NWORK-1){
        unsigned exp = 0u;
        __hip_atomic_compare_exchange_strong(winner, &exp, xcd+1u,
            __ATOMIC_RELAXED, __ATOMIC_RELAXED, __HIP_MEMORY_SCOPE_AGENT);
      }
      unsigned w;
      do { w = __hip_atomic_load(winner, __ATOMIC_RELAXED,
                                 __HIP_MEMORY_SCOPE_AGENT); }
      while (w == 0u);                   // terminates by pigeonhole
      if (w == xcd+1u) slot = (int)rank;
    }
    s_slot = slot;
  }
  __syncthreads();
  const int slot = s_slot;
  if (slot < 0) return;

  // ---- stage weight slice -> LDS, XOR-swizzled.
  const int jbase = slot * COLS;
  for (int cidx = threadIdx.x; cidx < 3*COLS*96; cidx += TPB){
    int g   = cidx / (COLS*96);
    int rem = cidx - g*(COLS*96);
    int col = rem / 96;
    int kch = rem - col*96;
    const uint4 v = *(const uint4*)(wbuf + ((size_t)(g*HDIM + jbase + col))*KDIM + kch*8);
    int off = (((g*COLS + col)*1536) + kch*16) ^ ((col & 7) << 4);
    *(uint4*)(wlds + off) = v;
  }
  __syncthreads();                       // last barrier; loop below is per-wave

  const int lane = threadIdx.x & 63;
  const int wave = threadIdx.x >> 6;     // rows 16*wave..16*wave+15
  const int c15  = lane & 15;
  const int kgrp = lane >> 4;
  const int arow = wave*16 + c15;
  const int n0   = wave*16 + kgrp*4;
  const int swz  = (c15 & 7) << 4;
  const int jcol0 = jbase + c15;
  const int jcol1 = jbase + 16 + c15;
  const int jc20  = jcol0 & ~1;
  const int jc21  = jcol1 & ~1;
  const int lz0 = ((0*COLS + c15     )*1536) + kgrp*16;
  const int lz1 = ((0*COLS + c15 + 16)*1536) + kgrp*16;
  const int lr0 = ((1*COLS + c15     )*1536) + kgrp*16;
  const int lr1 = ((1*COLS + c15 + 16)*1536) + kgrp*16;
  const int lh0 = ((2*COLS + c15     )*1536) + kgrp*16;
  const int lh1 = ((2*COLS + c15 + 16)*1536) + kgrp*16;
  const float bzj0 = bz[jcol0], bzj1 = bz[jcol1];
  const float brj0 = br[jcol0], brj1 = br[jcol1];
  const float bhj0 = bh[jcol0], bhj1 = bh[jcol1];
  const u64* hrowL = (const u64*)hxL + (size_t)arow*128 + kgrp*2;  // + kc*8 (+1)
  const u64* hrowM = (const u64*)hxM + (size_t)arow*128 + kgrp*2;
  const u64* rrowL = (const u64*)rhL + (size_t)arow*128 + kgrp*2;
  const u64* rrowM = (const u64*)rhM + (size_t)arow*128 + kgrp*2;
  unsigned* myhflL = hflL + wave*NWORK;
  unsigned* myhflM = hflM + wave*NWORK;
  unsigned* myrflL = rflL + wave*NWORK;
  unsigned* myrflM = rflM + wave*NWORK;
  float hreg0[4] = {0,0,0,0}, hreg1[4] = {0,0,0,0};
  int fpd = 0;                           // sticky: fast path dead

  u64 q[32];
  f16x8 aeA[8], aeB[8];

#define LOADQ_FAST(BASE) do {                                                 \
    asm volatile("buffer_inv" ::: "memory");                                  \
    _Pragma("unroll")                                                         \
    for (int kc = 0; kc < 16; ++kc){                                          \
      q[2*kc]   = (BASE)[kc*8];                                               \
      q[2*kc+1] = (BASE)[kc*8 + 1];                                           \
    }                                                                         \
  } while (0)

#define LOADQ_MALL(BASE) do {                                                 \
    _Pragma("unroll")                                                         \
    for (int kc = 0; kc < 16; ++kc){                                          \
      q[2*kc]   = __hip_atomic_load((BASE) + kc*8,     __ATOMIC_RELAXED,      \
                                    __HIP_MEMORY_SCOPE_AGENT);                \
      q[2*kc+1] = __hip_atomic_load((BASE) + kc*8 + 1, __ATOMIC_RELAXED,      \
                                    __HIP_MEMORY_SCOPE_AGENT);                \
    }                                                                         \
  } while (0)

  // Prefetch e fragments for t = 0.
  {
    const _Float16* ae0 = ebuf + (size_t)arow*EDIM + kgrp*8;
    #pragma unroll
    for (int kc = 0; kc < 8; ++kc) aeA[kc] = *(const f16x8*)(ae0 + kc*32);
  }

  for (int t = 0; t < LSTEPS; ++t){
    const unsigned tagn = (unsigned)(t + 1);

    // ======== phase 1: r gate ========
    f32x4 accr0 = {0,0,0,0}, accr1 = {0,0,0,0};
    #pragma unroll
    for (int kc = 0; kc < 8; ++kc){
      f16x8 b0 = *(const f16x8*)(wlds + ((lr0 + (16+kc)*64) ^ swz));
      f16x8 b1 = *(const f16x8*)(wlds + ((lr1 + (16+kc)*64) ^ swz));
      accr0 = MFMA(aeA[kc], b0, accr0, 0, 0, 0);
      accr1 = MFMA(aeA[kc], b1, accr1, 0, 0, 0);
    }
    // pre-wait: drain (poll would pay this anyway) + deferred MALL h-flag(t).
    VMDRAIN();                           // prev MALL h data + out + prefetch done
    if (lane == 0)
      __hip_atomic_store(&myhflM[slot], (unsigned)t,
                         __ATOMIC_RELAXED, __HIP_MEMORY_SCOPE_AGENT);
    {
      int fb = waitx(myhflL, myhflM, (unsigned)t, fpd);   // t=0: zeros pass
      fpd |= fb;
      if (fb) LOADQ_MALL(hrowM); else LOADQ_FAST(hrowL);
    }
    #pragma unroll
    for (int kc = 0; kc < 16; ++kc){
      f16x8 a  = AFU(q[2*kc], q[2*kc+1]);
      f16x8 b0 = *(const f16x8*)(wlds + ((lr0 + kc*64) ^ swz));
      f16x8 b1 = *(const f16x8*)(wlds + ((lr1 + kc*64) ^ swz));
      accr0 = MFMA(a, b0, accr0, 0, 0, 0);
      accr1 = MFMA(a, b1, accr1, 0, 0, 0);
    }
    unsigned w00, w01, w10, w11; int rr;
    {
      float rh0[4], rh1[4];
      #pragma unroll
      for (int i = 0; i < 4; ++i){
        rh0[i] = sigm(accr0[i] + brj0) * hreg0[i];
        rh1[i] = sigm(accr1[i] + brj1) * hreg1[i];
      }
      pack2(lane, rh0[0], rh0[1], rh0[2], rh0[3], &w00, &w01, &rr);
      pack2(lane, rh1[0], rh1[1], rh1[2], rh1[3], &w10, &w11, &rr);
    }
    const int r0 = n0 + rr;
    // fast publish: plain stores -> L2-ack drain -> plain flag.
    *(unsigned*)(rhL + (size_t)r0*HDIM + jc20)     = w00;
    *(unsigned*)(rhL + (size_t)(r0+1)*HDIM + jc20) = w01;
    *(unsigned*)(rhL + (size_t)r0*HDIM + jc21)     = w10;
    *(unsigned*)(rhL + (size_t)(r0+1)*HDIM + jc21) = w11;
    VMDRAIN();                           // L2 acks only (MALL ops long drained)
    if (lane == 0) *(volatile unsigned*)&myrflL[slot] = tagn;
    // MALL mirror: fire & forget (drained at phase-2 pre-wait).
    __hip_atomic_store((unsigned*)(rhM + (size_t)r0*HDIM + jc20),     w00,
                       __ATOMIC_RELAXED, __HIP_MEMORY_SCOPE_AGENT);
    __hip_atomic_store((unsigned*)(rhM + (size_t)(r0+1)*HDIM + jc20), w01,
                       __ATOMIC_RELAXED, __HIP_MEMORY_SCOPE_AGENT);
    __hip_atomic_store((unsigned*)(rhM + (size_t)r0*HDIM + jc21),     w10,
                       __ATOMIC_RELAXED, __HIP_MEMORY_SCOPE_AGENT);
    __hip_atomic_store((unsigned*)(rhM + (size_t)(r0+1)*HDIM + jc21), w11,
                       __ATOMIC_RELAXED, __HIP_MEMORY_SCOPE_AGENT);
    // e(t+1) prefetch (consumed next step; drained at phase-2 pre-wait).
    {
      const int tn = (t + 1 < LSTEPS) ? (t + 1) : t;
      const _Float16* aen = ebuf + ((size_t)tn*NBATCH + arow)*EDIM + kgrp*8;
      #pragma unroll
      for (int kc = 0; kc < 8; ++kc) aeB[kc] = *(const f16x8*)(aen + kc*32);
    }

    // ======== phase-2 cover: z (h frags in regs) + z,h~ e-parts ========
    f32x4 accz0 = {0,0,0,0}, accz1 = {0,0,0,0};
    f32x4 acch0 = {0,0,0,0}, acch1 = {0,0,0,0};
    #pragma unroll
    for (int kc = 0; kc < 16; ++kc){
      f16x8 a  = AFU(q[2*kc], q[2*kc+1]);
      f16x8 b0 = *(const f16x8*)(wlds + ((lz0 + kc*64) ^ swz));
      f16x8 b1 = *(const f16x8*)(wlds + ((lz1 + kc*64) ^ swz));
      accz0 = MFMA(a, b0, accz0, 0, 0, 0);
      accz1 = MFMA(a, b1, accz1, 0, 0, 0);
    }
    #pragma unroll
    for (int kc = 0; kc < 8; ++kc){
      f16x8 z0 = *(const f16x8*)(wlds + ((lz0 + (16+kc)*64) ^ swz));
      f16x8 z1 = *(const f16x8*)(wlds + ((lz1 + (16+kc)*64) ^ swz));
      f16x8 h0 = *(const f16x8*)(wlds + ((lh0 + (16+kc)*64) ^ swz));
      f16x8 h1 = *(const f16x8*)(wlds + ((lh1 + (16+kc)*64) ^ swz));
      accz0 = MFMA(aeA[kc], z0, accz0, 0, 0, 0);
      accz1 = MFMA(aeA[kc], z1, accz1, 0, 0, 0);
      acch0 = MFMA(aeA[kc], h0, acch0, 0, 0, 0);
      acch1 = MFMA(aeA[kc], h1, acch1, 0, 0, 0);
    }
    float zreg0[4], zreg1[4];
    #pragma unroll
    for (int i = 0; i < 4; ++i){
      zreg0[i] = sigm(accz0[i] + bzj0);
      zreg1[i] = sigm(accz1[i] + bzj1);
    }

    // ======== phase 2: h~ ========
    VMDRAIN();                           // MALL rh mirror + aeB prefetch done
    if (lane == 0)
      __hip_atomic_store(&myrflM[slot], tagn,
                         __ATOMIC_RELAXED, __HIP_MEMORY_SCOPE_AGENT);
    {
      int fb = waitx(myrflL, myrflM, tagn, fpd);
      fpd |= fb;
      if (fb) LOADQ_MALL(rrowM); else LOADQ_FAST(rrowL);
    }
    #pragma unroll
    for (int kc = 0; kc < 16; ++kc){
      f16x8 a  = AFU(q[2*kc], q[2*kc+1]);
      f16x8 b0 = *(const f16x8*)(wlds + ((lh0 + kc*64) ^ swz));
      f16x8 b1 = *(const f16x8*)(wlds + ((lh1 + kc*64) ^ swz));
      acch0 = MFMA(a, b0, acch0, 0, 0, 0);
      acch1 = MFMA(a, b1, acch1, 0, 0, 0);
    }
    #pragma unroll
    for (int i = 0; i < 4; ++i){
      float ht0 = tanh_fast(acch0[i] + bhj0);
      float ht1 = tanh_fast(acch1[i] + bhj1);
      hreg0[i] = hreg0[i] + zreg0[i]*(ht0 - hreg0[i]);
      hreg1[i] = hreg1[i] + zreg1[i]*(ht1 - hreg1[i]);
    }
    {
      unsigned v00, v01, v10, v11; int rr2;
      pack2(lane, hreg0[0], hreg0[1], hreg0[2], hreg0[3], &v00, &v01, &rr2);
      pack2(lane, hreg1[0], hreg1[1], hreg1[2], hreg1[3], &v10, &v11, &rr2);
      const int s0 = n0 + rr2;
      *(unsigned*)(hxL + (size_t)s0*HDIM + jc20)     = v00;
      *(unsigned*)(hxL + (size_t)(s0+1)*HDIM + jc20) = v01;
      *(unsigned*)(hxL + (size_t)s0*HDIM + jc21)     = v10;
      *(unsigned*)(hxL + (size_t)(s0+1)*HDIM + jc21) = v11;
      VMDRAIN();                         // L2 acks only
      if (lane == 0) *(volatile unsigned*)&myhflL[slot] = tagn;
      __hip_atomic_store((unsigned*)(hxM + (size_t)s0*HDIM + jc20),     v00,
                         __ATOMIC_RELAXED, __HIP_MEMORY_SCOPE_AGENT);
      __hip_atomic_store((unsigned*)(hxM + (size_t)(s0+1)*HDIM + jc20), v01,
                         __ATOMIC_RELAXED, __HIP_MEMORY_SCOPE_AGENT);
      __hip_atomic_store((unsigned*)(hxM + (size_t)s0*HDIM + jc21),     v10,
                         __ATOMIC_RELAXED, __HIP_MEMORY_SCOPE_AGENT);
      __hip_atomic_store((unsigned*)(hxM + (size_t)(s0+1)*HDIM + jc21), v11,
                         __ATOMIC_RELAXED, __HIP_MEMORY_SCOPE_AGENT);
    }
    // out[t]: fire & forget (drained at next phase-1 pre-wait).
    #pragma unroll
    for (int i = 0; i < 4; ++i){
      int n = n0 + i;
      out[((size_t)t*NBATCH + n)*HDIM + jcol0] = hreg0[i];
      out[((size_t)t*NBATCH + n)*HDIM + jcol1] = hreg1[i];
    }
    #pragma unroll
    for (int kc = 0; kc < 8; ++kc) aeA[kc] = aeB[kc];
  }
}

extern "C" void kernel_launch(void* const* d_in, const int* in_sizes, int n_in,
                              void* d_out, int out_size, void* d_ws, size_t ws_size,
                              hipStream_t stream) {
  const int*   x   = (const int*)  d_in[0];
  const float* emb = (const float*)d_in[1];
  const float* Wz  = (const float*)d_in[2];
  const float* bz  = (const float*)d_in[3];
  const float* Wr  = (const float*)d_in[4];
  const float* br  = (const float*)d_in[5];
  const float* Wh  = (const float*)d_in[6];
  const float* bh  = (const float*)d_in[7];
  float* out = (float*)d_out;
  char*  ws  = (char*)d_ws;

  size_t off = 0;
  unsigned* xcnt   = (unsigned*)(ws + off); off += 64;
  unsigned* winner = (unsigned*)(ws + off); off += 64;
  unsigned* hflL = (unsigned*)(ws + off); off += 4*NWORK*4;   // 256
  unsigned* hflM = (unsigned*)(ws + off); off += 4*NWORK*4;
  unsigned* rflL = (unsigned*)(ws + off); off += 4*NWORK*4;
  unsigned* rflM = (unsigned*)(ws + off); off += 4*NWORK*4;
  _Float16* hxL  = (_Float16*)(ws + off); off += (size_t)NBATCH*HDIM*2;  // 65536
  _Float16* hxM  = (_Float16*)(ws + off); off += (size_t)NBATCH*HDIM*2;
  size_t zero_bytes = off;               // claim + flags + h copies start at 0
  _Float16* rhL  = (_Float16*)(ws + off); off += (size_t)NBATCH*HDIM*2;
  _Float16* rhM  = (_Float16*)(ws + off); off += (size_t)NBATCH*HDIM*2;
  _Float16* wbuf = (_Float16*)(ws + off); off += (size_t)3*HDIM*KDIM*2;        // 2359296
  _Float16* ebuf = (_Float16*)(ws + off); off += (size_t)LSTEPS*NBATCH*EDIM*2; // 16777216

  hipMemsetAsync(ws, 0, zero_bytes, stream);

  prep_w  <<<(3*HDIM*KDIM)/256,          256, 0, stream>>>(Wz, Wr, Wh, wbuf);
  prep_emb<<<(LSTEPS*NBATCH*EDIM/4)/256, 256, 0, stream>>>(x, emb, ebuf);
  gru_persist<<<NLAUNCH, TPB, 0, stream>>>(wbuf, ebuf, bz, br, bh,
                                           hxL, hxM, rhL, rhM,
                                           hflL, hflM, rflL, rflM,
                                           xcnt, winner, out);
}